// Round 4
// baseline (529.322 us; speedup 1.0000x reference)
//
#include <hip/hip_runtime.h>
#include <hip/hip_cooperative_groups.h>

namespace cg = cooperative_groups;

#define T_LEN 4096
#define H 16
#define N 16
#define D 64
#define NC 128
#define CL (T_LEN / NC)      // 32
#define WPB 8                // waves per block
#define NBLK (NC * H / WPB)  // 256 blocks, 512 threads each

// One fused cooperative kernel.
//   Phase A: wave g=(c,h) local scan from 0. Keeps out_local[CL] and a[CL]
//            in VGPRs, C-panel in LDS. Writes L[c][h][n][d], P[h][c].
//   Phase B: wave 0 of each block: serial cross-chunk combine (64-deep
//            prefetch), overwrites L with chunk ENTRY states, writes carry.
//   Phase C: out[t] = out_local[t] + pa(t) * (C_t . entry)  -- linearity of
//            the recurrence; no re-scan, no x/B re-read.
__global__ __launch_bounds__(WPB * 64)
void mamba_fused(const float* __restrict__ x, const float* __restrict__ dt,
                 const float* __restrict__ B, const float* __restrict__ C,
                 const float* __restrict__ mask, const float* __restrict__ ic,
                 const float* __restrict__ ld, const float* __restrict__ sw,
                 float* __restrict__ out, float* __restrict__ Lbuf,
                 float* __restrict__ Pbuf) {
    const int tid = threadIdx.x;
    const int wv = tid >> 6, d = tid & 63;
    const int g = blockIdx.x * WPB + wv;   // pair index
    const int c = g >> 4, h = g & 15;      // block covers one chunk, 8 heads
    const int t0 = c * CL;
    const float rate = -__expf(ld[h]);

    __shared__ float Bs[WPB][CL * N];      // dt-scaled B panel, 16 KB
    __shared__ float Cs[WPB][CL * N];      // C panel, 16 KB

    // ---- stage panels (B pre-scaled by dt) ----
    {
        const float4* Bg = (const float4*)B;
        const float4* Cg = (const float4*)C;
        float4* Bsv = (float4*)Bs[wv];
        float4* Csv = (float4*)Cs[wv];
#pragma unroll
        for (int i = 0; i < 2; ++i) {
            const int j = i * 64 + d;
            const int row = j >> 2, off = j & 3;
            const float dtv = dt[(t0 + row) * H + h];
            float4 bv = Bg[((t0 + row) * H + h) * (N / 4) + off];
            bv.x *= dtv; bv.y *= dtv; bv.z *= dtv; bv.w *= dtv;
            Bsv[j] = bv;
            Csv[j] = Cg[((t0 + row) * H + h) * (N / 4) + off];
        }
    }

    // ---- per-step decay ã and x loads ----
    float xw[CL], aa[CL];
#pragma unroll
    for (int ss = 0; ss < CL; ++ss)
        xw[ss] = x[((t0 + ss) * H + h) * D + d];
#pragma unroll
    for (int ss = 0; ss < CL; ++ss) {
        const float dtv = dt[(t0 + ss) * H + h];
        const float mv  = mask[t0 + ss];
        aa[ss] = (1.f - mv) * __expf(dtv * rate);
    }
    __syncthreads();

    // ---- Phase A: local scan; out_local overwrites xw ----
    float s[N];
#pragma unroll
    for (int n = 0; n < N; ++n) s[n] = 0.f;
    const float swv = sw[h * D + d];
    float P = 1.f;
#pragma unroll
    for (int ss = 0; ss < CL; ++ss) {
        const float a  = aa[ss];
        const float xv = xw[ss];
        const float* Br = Bs[wv] + ss * N;
        const float* Cr = Cs[wv] + ss * N;
        P *= a;
        float acc = swv * xv;
#pragma unroll
        for (int n = 0; n < N; ++n) {
            s[n] = a * s[n] + Br[n] * xv;   // Br already includes dt
            acc += Cr[n] * s[n];
        }
        xw[ss] = acc;                        // out_local
    }
    {
        float* Lp = Lbuf + ((c * H + h) * N) * D + d;
#pragma unroll
        for (int n = 0; n < N; ++n) Lp[n * D] = s[n];
        if (d == 0) Pbuf[h * NC + c] = P;
    }

    cg::this_grid().sync();

    // ---- Phase B: wave 0 of each block (1 wave/CU spread) ----
    if (wv == 0) {
        const int idx = blockIdx.x * 64 + d;   // 0..16383 = h*1024+n*64+d
        const int hh = idx >> 10;              // block-uniform
        float carry = ic[idx];
#pragma unroll
        for (int r = 0; r < NC / 64; ++r) {
            float l[64];
#pragma unroll
            for (int k = 0; k < 64; ++k)
                l[k] = Lbuf[(r * 64 + k) * (H * N * D) + idx];
#pragma unroll
            for (int k = 0; k < 64; ++k) {
                const float p = Pbuf[hh * NC + r * 64 + k];
                Lbuf[(r * 64 + k) * (H * N * D) + idx] = carry;  // entry
                carry = p * carry + l[k];
            }
        }
        out[idx] = carry;                      // next_carry
    }

    cg::this_grid().sync();

    // ---- Phase C: entry correction, fused output ----
    float E[N];
    {
        const float* Ep = Lbuf + ((c * H + h) * N) * D + d;
#pragma unroll
        for (int n = 0; n < N; ++n) E[n] = Ep[n * D];
    }
    float pa = 1.f;
    float* outp = out + H * N * D;
#pragma unroll
    for (int ss = 0; ss < CL; ++ss) {
        pa *= aa[ss];
        const float* Cr = Cs[wv] + ss * N;
        float corr = 0.f;
#pragma unroll
        for (int n = 0; n < N; ++n) corr += Cr[n] * E[n];
        outp[((t0 + ss) * H + h) * D + d] = xw[ss] + pa * corr;
    }
}

extern "C" void kernel_launch(void* const* d_in, const int* in_sizes, int n_in,
                              void* d_out, int out_size, void* d_ws, size_t ws_size,
                              hipStream_t stream) {
    const float* x    = (const float*)d_in[0];
    const float* dt   = (const float*)d_in[1];
    const float* B    = (const float*)d_in[2];
    const float* C    = (const float*)d_in[3];
    const float* mask = (const float*)d_in[4];
    const float* ic   = (const float*)d_in[5];
    const float* ld   = (const float*)d_in[6];
    const float* sw   = (const float*)d_in[7];
    float* out = (float*)d_out;

    float* Lbuf = (float*)d_ws;                      // NC*H*N*D floats
    float* Pbuf = Lbuf + (size_t)NC * H * N * D;     // H*NC floats

    void* args[] = {(void*)&x, (void*)&dt, (void*)&B, (void*)&C,
                    (void*)&mask, (void*)&ic, (void*)&ld, (void*)&sw,
                    (void*)&out, (void*)&Lbuf, (void*)&Pbuf};
    hipLaunchCooperativeKernel((void*)mamba_fused, dim3(NBLK), dim3(WPB * 64),
                               args, 0, stream);
}

// Round 6
// 469.197 us; speedup vs baseline: 1.1281x; 1.1281x over previous
//
#include <hip/hip_runtime.h>
#include <hip/hip_cooperative_groups.h>

namespace cg = cooperative_groups;

#define T_LEN 4096
#define H 16
#define N 16
#define D 64
#define NC 128
#define CL (T_LEN / NC)      // 32
#define WPB 8                // waves per block (512 threads)
#define NBLK (NC * H / WPB)  // 256 blocks -- one per CU, co-residency safe

// One fused cooperative kernel (round-4 geometry, spill-free regalloc).
//   Phase A: wave g=(c,h): local scan from 0 with fused C-projection;
//            keeps out_local[CL] in VGPRs. Writes L[c][h][n][d], P[h][c].
//   Phase B: wave 0 of each of the 256 blocks (1 wave/CU): serial
//            cross-chunk combine, 64-deep prefetch; overwrites L with
//            chunk ENTRY states; writes next_carry.
//   Phase C: out[t] = out_local[t] + pa(t) * (C_t . entry)  (linearity).
//            ã recomputed from dt/mask (L2-resident s_loads) - no aa[].
__global__ __launch_bounds__(WPB * 64, 2)   // VGPR cap 256: xw[32] stays in regs
void mamba_fused(const float* __restrict__ x, const float* __restrict__ dt,
                 const float* __restrict__ B, const float* __restrict__ C,
                 const float* __restrict__ mask, const float* __restrict__ ic,
                 const float* __restrict__ ld, const float* __restrict__ sw,
                 float* __restrict__ out, float* __restrict__ Lbuf,
                 float* __restrict__ Pbuf) {
    const int tid = threadIdx.x;
    const int wv = tid >> 6, d = tid & 63;
    const int g = blockIdx.x * WPB + wv;   // (chunk, head) pair index
    const int c = g >> 4, h = g & 15;
    const int t0 = c * CL;
    const float rate = -__expf(ld[h]);

    __shared__ float Bs[WPB][CL * N];      // dt-scaled B panel, 16 KB
    __shared__ float Cs[WPB][CL * N];      // C panel, 16 KB

    // ---- stage panels (B pre-scaled by dt), coalesced float4 ----
    {
        const float4* Bg = (const float4*)B;
        const float4* Cg = (const float4*)C;
        float4* Bsv = (float4*)Bs[wv];
        float4* Csv = (float4*)Cs[wv];
#pragma unroll
        for (int i = 0; i < 2; ++i) {
            const int j = i * 64 + d;
            const int row = j >> 2, off = j & 3;
            const float dtv = dt[(t0 + row) * H + h];
            float4 bv = Bg[((t0 + row) * H + h) * (N / 4) + off];
            bv.x *= dtv; bv.y *= dtv; bv.z *= dtv; bv.w *= dtv;
            Bsv[j] = bv;
            Csv[j] = Cg[((t0 + row) * H + h) * (N / 4) + off];
        }
    }

    // ---- x tile in registers (becomes out_local) ----
    float xw[CL];
#pragma unroll
    for (int ss = 0; ss < CL; ++ss)
        xw[ss] = x[((t0 + ss) * H + h) * D + d];
    __syncthreads();

    // ---- Phase A: local scan + fused C-projection ----
    float s[N];
#pragma unroll
    for (int n = 0; n < N; ++n) s[n] = 0.f;
    const float swv = sw[h * D + d];
    float P = 1.f;
#pragma unroll
    for (int ss = 0; ss < CL; ++ss) {
        const float dtv = dt[(t0 + ss) * H + h];   // wave-uniform s_load
        const float mv  = mask[t0 + ss];
        const float a   = (1.f - mv) * __expf(dtv * rate);
        const float xv  = xw[ss];
        P *= a;
        float acc = swv * xv;
        const float4* Br4 = (const float4*)(Bs[wv] + ss * N);
        const float4* Cr4 = (const float4*)(Cs[wv] + ss * N);
#pragma unroll
        for (int q = 0; q < 4; ++q) {               // ds_read_b128 broadcasts
            const float4 bv = Br4[q];
            const float4 cv = Cr4[q];
            s[4*q+0] = a * s[4*q+0] + bv.x * xv;  acc += cv.x * s[4*q+0];
            s[4*q+1] = a * s[4*q+1] + bv.y * xv;  acc += cv.y * s[4*q+1];
            s[4*q+2] = a * s[4*q+2] + bv.z * xv;  acc += cv.z * s[4*q+2];
            s[4*q+3] = a * s[4*q+3] + bv.w * xv;  acc += cv.w * s[4*q+3];
        }
        xw[ss] = acc;                               // out_local
    }
    {
        float* Lp = Lbuf + ((c * H + h) * N) * D + d;
#pragma unroll
        for (int n = 0; n < N; ++n) Lp[n * D] = s[n];
        if (d == 0) Pbuf[h * NC + c] = P;
    }

    cg::this_grid().sync();

    // ---- Phase B: wave 0 of each block -> 16384 lanes, 1 wave/CU ----
    if (wv == 0) {
        const int idx = blockIdx.x * 64 + d;        // h*1024 + n*64 + d
        const int hh = idx >> 10;                   // wave-uniform
        float carry = ic[idx];
#pragma unroll
        for (int r = 0; r < NC / 64; ++r) {
            float l[64];
#pragma unroll
            for (int k = 0; k < 64; ++k)
                l[k] = Lbuf[(r * 64 + k) * (H * N * D) + idx];
#pragma unroll
            for (int k = 0; k < 64; ++k) {
                const float p = Pbuf[hh * NC + r * 64 + k];  // s_load
                Lbuf[(r * 64 + k) * (H * N * D) + idx] = carry;  // entry
                carry = p * carry + l[k];
            }
        }
        out[idx] = carry;                           // next_carry
    }

    cg::this_grid().sync();

    // ---- Phase C: entry correction, ã recomputed (no aa[] array) ----
    float E[N];
    {
        const float* Ep = Lbuf + ((c * H + h) * N) * D + d;
#pragma unroll
        for (int n = 0; n < N; ++n) E[n] = Ep[n * D];
    }
    float pa = 1.f;
    float* outp = out + H * N * D;
#pragma unroll
    for (int ss = 0; ss < CL; ++ss) {
        const float dtv = dt[(t0 + ss) * H + h];    // L2-resident s_load
        const float mv  = mask[t0 + ss];
        pa *= (1.f - mv) * __expf(dtv * rate);
        const float4* Cr4 = (const float4*)(Cs[wv] + ss * N);
        float corr = 0.f;
#pragma unroll
        for (int q = 0; q < 4; ++q) {
            const float4 cv = Cr4[q];
            corr += cv.x * E[4*q+0] + cv.y * E[4*q+1]
                  + cv.z * E[4*q+2] + cv.w * E[4*q+3];
        }
        outp[((t0 + ss) * H + h) * D + d] = xw[ss] + pa * corr;
    }
}

extern "C" void kernel_launch(void* const* d_in, const int* in_sizes, int n_in,
                              void* d_out, int out_size, void* d_ws, size_t ws_size,
                              hipStream_t stream) {
    const float* x    = (const float*)d_in[0];
    const float* dt   = (const float*)d_in[1];
    const float* B    = (const float*)d_in[2];
    const float* C    = (const float*)d_in[3];
    const float* mask = (const float*)d_in[4];
    const float* ic   = (const float*)d_in[5];
    const float* ld   = (const float*)d_in[6];
    const float* sw   = (const float*)d_in[7];
    float* out = (float*)d_out;

    float* Lbuf = (float*)d_ws;                      // NC*H*N*D floats
    float* Pbuf = Lbuf + (size_t)NC * H * N * D;     // H*NC floats

    void* args[] = {(void*)&x, (void*)&dt, (void*)&B, (void*)&C,
                    (void*)&mask, (void*)&ic, (void*)&ld, (void*)&sw,
                    (void*)&out, (void*)&Lbuf, (void*)&Pbuf};
    hipLaunchCooperativeKernel((void*)mamba_fused, dim3(NBLK), dim3(WPB * 64),
                               args, 0, stream);
}